// Round 4
// baseline (654.960 us; speedup 1.0000x reference)
//
#include <hip/hip_runtime.h>

typedef short bf16x8 __attribute__((ext_vector_type(8)));
typedef float f32x4 __attribute__((ext_vector_type(4)));
typedef unsigned short u16;
typedef u16 ushort8v __attribute__((ext_vector_type(8)));

// ---- constants ----
#define VOCAB 100000
#define EMB 300
#define SEQ 40
#define BATCH 8192
#define COUT 210
#define NBLK 5
#define KPOOL 38
#define DH 35
#define NCLS 35
#define PADROWS 42          // 1 zero row + 40 seq + 1 zero row
#define PCOL 320            // padded emb row (3*320 = 960 = 30*32)
#define KDIM 960
#define NUSE 192            // only channels 0..189 feed the pool; compute 12 n-tiles
#define BM 128

__device__ __forceinline__ u16 f2bf(float f) {
  unsigned u = __float_as_uint(f);
  unsigned r = 0x7FFFu + ((u >> 16) & 1u);
  return (u16)((u + r) >> 16);
}

// ---- kernel 1: embedding gather -> padded bf16 [BATCH][42][320] ----
__global__ __launch_bounds__(256) void k_gather(const int* __restrict__ x,
                                                const float* __restrict__ w2v,
                                                u16* __restrict__ embp) {
  int g = blockIdx.x * 256 + threadIdx.x;      // 8192*42*40 chunks of 8 bf16
  int r = g / 40, ck = g - r * 40;
  int b = r / PADROWS, sp = r - b * PADROWS;
  float v[8] = {0.f, 0.f, 0.f, 0.f, 0.f, 0.f, 0.f, 0.f};
  if (sp >= 1 && sp <= SEQ && ck <= 37) {
    int idx = x[b * SEQ + sp - 1];
    const float* src = w2v + (size_t)idx * EMB + ck * 8;
    float4 f0 = *(const float4*)src;           // w2v rows are 1200B -> 16B aligned
    v[0] = f0.x; v[1] = f0.y; v[2] = f0.z; v[3] = f0.w;
    if (ck < 37) {
      float4 f1 = *(const float4*)(src + 4);
      v[4] = f1.x; v[5] = f1.y; v[6] = f1.z; v[7] = f1.w;
    }
  }
  ushort8v o;
#pragma unroll
  for (int j = 0; j < 8; ++j) o[j] = f2bf(v[j]);
  *(ushort8v*)(embp + (size_t)g * 8) = o;
}

// ---- kernel 2: conv_w [3][300][210] -> Bt bf16 [192 cols][960 k] (zero padded) ----
__global__ __launch_bounds__(256) void k_prepB(const float* __restrict__ convw,
                                               u16* __restrict__ Bt) {
  int id = blockIdx.x * 256 + threadIdx.x;     // 192*960 = 184320
  if (id >= NUSE * KDIM) return;
  int col = id / KDIM, k = id - col * KDIM;
  int kh = k / PCOL, e = k - kh * PCOL;
  float v = (e < EMB) ? convw[(kh * EMB + e) * COUT + col] : 0.f;
  Bt[id] = f2bf(v);
}

// ---- kernel 3: conv GEMM (M=327680, N=192, K=960) + bias + relu + channel-group max ----
// NO LDS in the main loop: MFMA fragments are loaded DIRECTLY global->VGPR.
// A-frag for 16x16x32: lane(l4,l15) needs A[row=..+l15][k=l4*8..+8] = 16 contiguous
// bytes of an embp row; one global_load_dwordx4 per frag covers 16 rows x 64B = 16
// full cachelines (coalesced). Same for Bt columns. Zero barriers, zero ds_read;
// 2-deep register pingpong (all indices static per rule #20).
__global__ __launch_bounds__(512, 4) void k_conv_gemm(const u16* __restrict__ embp,
                                                      const u16* __restrict__ Bt,
                                                      const float* __restrict__ convb,
                                                      float* __restrict__ maxc) {
  __shared__ __align__(16) float act[32 * 194];   // epilogue only (24832 B)

  const int tid = threadIdx.x;
  const int lane = tid & 63;
  const int w = tid >> 6;
  const int wr = w >> 2, wc = w & 3;
  const int l15 = lane & 15, l4 = lane >> 4;
  const int m0 = blockIdx.x * BM;

  // per-lane fragment base pointers (element units); step s adds s*32 elements
  const u16* pa0; const u16* pa1; const u16* pa2; const u16* pa3;
  {
    int rowm, ab, as_;
    rowm = m0 + wr * 64 + 0  + l15; ab = rowm / SEQ; as_ = rowm - ab * SEQ;
    pa0 = embp + (size_t)(ab * PADROWS + as_) * PCOL + l4 * 8;
    rowm = m0 + wr * 64 + 16 + l15; ab = rowm / SEQ; as_ = rowm - ab * SEQ;
    pa1 = embp + (size_t)(ab * PADROWS + as_) * PCOL + l4 * 8;
    rowm = m0 + wr * 64 + 32 + l15; ab = rowm / SEQ; as_ = rowm - ab * SEQ;
    pa2 = embp + (size_t)(ab * PADROWS + as_) * PCOL + l4 * 8;
    rowm = m0 + wr * 64 + 48 + l15; ab = rowm / SEQ; as_ = rowm - ab * SEQ;
    pa3 = embp + (size_t)(ab * PADROWS + as_) * PCOL + l4 * 8;
  }
  const u16* pb0 = Bt + (wc * 48 + 0  + l15) * KDIM + l4 * 8;
  const u16* pb1 = Bt + (wc * 48 + 16 + l15) * KDIM + l4 * 8;
  const u16* pb2 = Bt + (wc * 48 + 32 + l15) * KDIM + l4 * 8;

  f32x4 acc[4][3];
  const f32x4 zero = {0.f, 0.f, 0.f, 0.f};
#pragma unroll
  for (int i = 0; i < 4; ++i)
#pragma unroll
    for (int j = 0; j < 3; ++j) acc[i][j] = zero;

  bf16x8 a0[4], b0[3], a1[4], b1[3];

#define LOADSET(AV, BV, OFS)                         \
  AV[0] = *(const bf16x8*)(pa0 + (OFS));             \
  AV[1] = *(const bf16x8*)(pa1 + (OFS));             \
  AV[2] = *(const bf16x8*)(pa2 + (OFS));             \
  AV[3] = *(const bf16x8*)(pa3 + (OFS));             \
  BV[0] = *(const bf16x8*)(pb0 + (OFS));             \
  BV[1] = *(const bf16x8*)(pb1 + (OFS));             \
  BV[2] = *(const bf16x8*)(pb2 + (OFS));

#define MFMASET(AV, BV)                                                               \
  _Pragma("unroll")                                                                   \
  for (int fm = 0; fm < 4; ++fm) {                                                    \
    _Pragma("unroll")                                                                 \
    for (int fn = 0; fn < 3; ++fn)                                                    \
      acc[fm][fn] = __builtin_amdgcn_mfma_f32_16x16x32_bf16(AV[fm], BV[fn], acc[fm][fn], 0, 0, 0); \
  }

  LOADSET(a0, b0, 0)
#pragma unroll 1
  for (int t = 0; t < 15; ++t) {
    LOADSET(a1, b1, 32)          // odd step 2t+1
    MFMASET(a0, b0)              // even step 2t
    if (t < 14) { LOADSET(a0, b0, 64) }   // even step 2t+2
    MFMASET(a1, b1)              // odd step 2t+1
    pa0 += 64; pa1 += 64; pa2 += 64; pa3 += 64;
    pb0 += 64; pb1 += 64; pb2 += 64;
  }
#undef LOADSET
#undef MFMASET

  // epilogue: 4 chunks of 32 rows; bias+relu -> LDS -> per-(row,group) max over 38 channels.
  // Fully unrolled: every acc[] index compile-time (rule #20).
#pragma unroll
  for (int ch = 0; ch < 4; ++ch) {
    if (wr == (ch >> 1)) {
      const int fbase = (ch & 1) * 2;
#pragma unroll
      for (int fi = 0; fi < 2; ++fi) {
#pragma unroll
        for (int fn = 0; fn < 3; ++fn) {
          const int col = wc * 48 + fn * 16 + l15;   // < 192 < 210
          const float bias = convb[col];
#pragma unroll
          for (int rg = 0; rg < 4; ++rg) {
            const int rloc = fi * 16 + l4 * 4 + rg;  // 0..31 within chunk
            float vv = acc[fbase + fi][fn][rg] + bias;
            act[rloc * 194 + col] = fmaxf(vv, 0.f);
          }
        }
      }
    }
    __syncthreads();
    if (tid < 160) {                                  // 32 rows x 5 groups
      const int rl = tid / 5, gq = tid - rl * 5;
      const float* ap = act + rl * 194 + gq * KPOOL;
      float mx = 0.f;                                 // relu => values >= 0
#pragma unroll
      for (int i = 0; i < KPOOL; ++i) mx = fmaxf(mx, ap[i]);
      const int m = m0 + ch * 32 + rl;
      const int bb = m / SEQ, ss = m - bb * SEQ;
      maxc[(bb * NBLK + gq) * SEQ + ss] = mx;         // unmasked max; mask applied in k_dense
    }
    __syncthreads();
  }
}

// ---- kernel 4: region-masked dense (120->35) + out (35->35) ----
__global__ __launch_bounds__(256) void k_dense(const float* __restrict__ maxc,
                                               const int* __restrict__ pos,
                                               const float* __restrict__ dw,
                                               const float* __restrict__ db,
                                               const float* __restrict__ ow,
                                               const float* __restrict__ ob,
                                               float* __restrict__ out) {
  __shared__ float dwL[120 * 36];
  __shared__ float owL[35 * 36];
  __shared__ float hL[64 * 36];
  __shared__ float mxL[64 * 40];
  const int tid = threadIdx.x;
  const int r0 = blockIdx.x * 64;                    // 640 blocks x 64 rows
  for (int i = tid; i < 120 * 35; i += 256) { int j = i / 35, d = i - j * 35; dwL[j * 36 + d] = dw[i]; }
  for (int i = tid; i < 35 * 35; i += 256)  { int j = i / 35, d = i - j * 35; owL[j * 36 + d] = ow[i]; }
  for (int i = tid; i < 64 * 40; i += 256)  mxL[i] = maxc[(size_t)r0 * 40 + i];
  __syncthreads();
  for (int t = tid; t < 64 * 35; t += 256) {
    const int row = t / 35, d = t - row * 35;
    const int rg = r0 + row;
    const int b = rg / NBLK;
    const int p0 = pos[b * 2], p1 = pos[b * 2 + 1];
    int e1 = min(p0, p1), e2 = max(p0, p1);
    if (e1 == 0) { e1 = 1; e2 += 1; }
    float a = db[d];
#pragma unroll
    for (int s = 0; s < SEQ; ++s) {
      const int k = (s >= e1) + (s >= e2);           // region of position s
      a += mxL[row * 40 + s] * dwL[(k * SEQ + s) * 36 + d];
    }
    hL[row * 36 + d] = a;
  }
  __syncthreads();
  for (int t = tid; t < 64 * 35; t += 256) {
    const int row = t / 35, c = t - row * 35;
    float a = ob[c];
#pragma unroll
    for (int d = 0; d < DH; ++d) a += hL[row * 36 + d] * owL[d * 36 + c];
    out[(size_t)(r0 + row) * NCLS + c] = a;
  }
}

extern "C" void kernel_launch(void* const* d_in, const int* in_sizes, int n_in,
                              void* d_out, int out_size, void* d_ws, size_t ws_size,
                              hipStream_t stream) {
  const int*   x     = (const int*)d_in[0];
  const int*   pos   = (const int*)d_in[1];
  const float* w2v   = (const float*)d_in[2];
  const float* convw = (const float*)d_in[3];
  const float* convb = (const float*)d_in[4];
  const float* dw    = (const float*)d_in[5];
  const float* db    = (const float*)d_in[6];
  const float* ow    = (const float*)d_in[7];
  const float* ob    = (const float*)d_in[8];
  float* out = (float*)d_out;

  char* ws = (char*)d_ws;
  u16* embp = (u16*)ws;                                   // 8192*42*320*2 = 220,200,960 B
  u16* Bt   = (u16*)(ws + 220200960);                     // 192*960*2    =     368,640 B
  float* maxc = (float*)(ws + 220200960 + 368640);        // 40960*40*4   =   6,553,600 B

  k_gather<<<53760, 256, 0, stream>>>(x, w2v, embp);      // 8192*42*40/256
  k_prepB<<<720, 256, 0, stream>>>(convw, Bt);            // 192*960/256
  k_conv_gemm<<<2560, 512, 0, stream>>>(embp, Bt, convb, maxc);  // 327680/128
  k_dense<<<640, 256, 0, stream>>>(maxc, pos, dw, db, ow, ob, out);
}

// Round 5
// 229.302 us; speedup vs baseline: 2.8563x; 2.8563x over previous
//
#include <hip/hip_runtime.h>

typedef short bf16x8 __attribute__((ext_vector_type(8)));
typedef float f32x4 __attribute__((ext_vector_type(4)));
typedef unsigned short u16;
typedef u16 ushort8v __attribute__((ext_vector_type(8)));

// ---- constants ----
#define VOCAB 100000
#define EMB 300
#define SEQ 40
#define BATCH 8192
#define COUT 210
#define NBLK 5
#define KPOOL 38
#define DH 35
#define NCLS 35
#define PCOL 320            // padded w2v row: 300 real + 20 zero (16B-aligned rows)
#define KDIM 960            // 3*320
#define NUSE 192            // only channels 0..189 feed the pool
#define BM 128
#define NGR 120             // KDIM/8 granules

__device__ __forceinline__ u16 f2bf(float f) {
  unsigned u = __float_as_uint(f);
  unsigned r = 0x7FFFu + ((u >> 16) & 1u);
  return (u16)((u + r) >> 16);
}

__device__ __forceinline__ void gload_lds16(void* lds, const void* g) {
  __builtin_amdgcn_global_load_lds(
      (const __attribute__((address_space(1))) void*)g,
      (__attribute__((address_space(3))) void*)lds, 16, 0, 0);
}

// ---- kernel 1: w2v f32 [VOCAB][300] -> W bf16 [VOCAB+1][320]; row VOCAB = zeros ----
__global__ __launch_bounds__(256) void k_prepW(const float* __restrict__ w2v,
                                               u16* __restrict__ W) {
  int id = blockIdx.x * 256 + threadIdx.x;          // (VOCAB+1)*40 chunks of 8
  if (id >= (VOCAB + 1) * 40) return;
  int v = id / 40, e8 = id - v * 40;
  int e = e8 * 8;
  float vals[8] = {0.f, 0.f, 0.f, 0.f, 0.f, 0.f, 0.f, 0.f};
  if (v < VOCAB) {
    const float* src = w2v + (size_t)v * EMB + e;
    if (e <= 292) {
      float4 f0 = *(const float4*)src;
      float4 f1 = *(const float4*)(src + 4);
      vals[0] = f0.x; vals[1] = f0.y; vals[2] = f0.z; vals[3] = f0.w;
      vals[4] = f1.x; vals[5] = f1.y; vals[6] = f1.z; vals[7] = f1.w;
    } else if (e == 296) {
      float4 f0 = *(const float4*)src;               // 296..299
      vals[0] = f0.x; vals[1] = f0.y; vals[2] = f0.z; vals[3] = f0.w;
    }
  }
  ushort8v o;
#pragma unroll
  for (int j = 0; j < 8; ++j) o[j] = f2bf(vals[j]);
  *(ushort8v*)(W + (size_t)v * PCOL + e) = o;
}

// ---- kernel 2: conv_w [3][300][210] -> Btn bf16 [120 gran][192 col][8] (zero padded) ----
__global__ __launch_bounds__(256) void k_prepB(const float* __restrict__ convw,
                                               u16* __restrict__ Btn) {
  int id = blockIdx.x * 256 + threadIdx.x;          // 120*192 = 23040
  if (id >= NGR * NUSE) return;
  int gg = id / NUSE, col = id - gg * NUSE;
  ushort8v o;
#pragma unroll
  for (int j = 0; j < 8; ++j) {
    int k = gg * 8 + j;
    int kh = (k >= 640) ? 2 : (k >= 320 ? 1 : 0);
    int e = k - kh * PCOL;
    float v = (e < EMB) ? convw[(kh * EMB + e) * COUT + col] : 0.f;
    o[j] = f2bf(v);
  }
  *(ushort8v*)(Btn + (size_t)id * 8) = o;
}

// ---- kernel 3: fused gather + conv GEMM (M=327680, N=192, K=960) + bias/relu/pool-max ----
// A is gathered per-lane from W via global_load_lds (no im2col tensor!). BK=32.
// 3 LDS A-bufs (8KB each), A staged 2 tiles ahead; B direct global->VGPR, 3 reg sets,
// 2 tiles ahead. Counted s_waitcnt vmcnt(7) per step (never drains prefetch).
__global__ __launch_bounds__(512, 2) void k_conv_gemm(const u16* __restrict__ Wb,
                                                      const u16* __restrict__ Btn,
                                                      const int* __restrict__ x,
                                                      const float* __restrict__ convb,
                                                      float* __restrict__ maxc) {
  __shared__ __align__(16) char smem[24832];        // 3 x 8192 A-bufs; epilogue act[32][194]
  float* act = (float*)smem;

  const int tid = threadIdx.x;
  const int lane = tid & 63;
  const int w = tid >> 6;
  const int wr = w >> 2, wc = w & 3;
  const int l15 = lane & 15, l4 = lane >> 4;
  const int m0 = blockIdx.x * BM;

  // --- A staging setup: thread stages chunk (granule ag=tid>>7, row ar=tid&127) ---
  const int ag = tid >> 7, ar = tid & 127;
  unsigned offm1, off0, offp1;                      // element offsets into W for 3 tokens
  {
    const int m = m0 + ar;
    const int b = m / SEQ, s = m - b * SEQ;
    const unsigned im1 = (s == 0)       ? VOCAB : (unsigned)x[b * SEQ + s - 1];
    const unsigned i0  =                           (unsigned)x[b * SEQ + s];
    const unsigned ip1 = (s == SEQ - 1) ? VOCAB : (unsigned)x[b * SEQ + s + 1];
    offm1 = im1 * PCOL; off0 = i0 * PCOL; offp1 = ip1 * PCOL;
  }

  // --- B direct-load setup ---
  const u16* pbB = Btn + (size_t)((l4 * NUSE) + wc * 48 + l15) * 8;

  const int aoffb = (l4 * 128 + wr * 64 + l15) * 16;  // + fm*256

  f32x4 acc[4][3];
  const f32x4 zero = {0.f, 0.f, 0.f, 0.f};
#pragma unroll
  for (int i = 0; i < 4; ++i)
#pragma unroll
    for (int j = 0; j < 3; ++j) acc[i][j] = zero;

  bf16x8 b0[3], b1[3], b2[3];

#define STAGEA(T, BSEL)                                                        \
  {                                                                            \
    const int koff_ = (T) * 32 + ag * 8;                                       \
    unsigned off_ = (koff_ < 320) ? (offm1 + koff_)                            \
                  : (koff_ < 640) ? (off0 + (koff_ - 320))                     \
                                  : (offp1 + (koff_ - 640));                   \
    gload_lds16(smem + (BSEL) * 8192 + tid * 16, Wb + off_);                   \
  }

#define LOADB(SET, T)                                                          \
  {                                                                            \
    const u16* p_ = pbB + (size_t)(T) * 6144;                                  \
    SET[0] = *(const bf16x8*)(p_);                                             \
    SET[1] = *(const bf16x8*)(p_ + 128);                                       \
    SET[2] = *(const bf16x8*)(p_ + 256);                                       \
  }

#define COMPUTE(BSEL, BUSE)                                                    \
  {                                                                            \
    const char* A_ = smem + (BSEL) * 8192;                                     \
    bf16x8 a0_ = *(const bf16x8*)(A_ + aoffb);                                 \
    bf16x8 a1_ = *(const bf16x8*)(A_ + aoffb + 256);                           \
    bf16x8 a2_ = *(const bf16x8*)(A_ + aoffb + 512);                           \
    bf16x8 a3_ = *(const bf16x8*)(A_ + aoffb + 768);                           \
    __builtin_amdgcn_s_setprio(1);                                             \
    _Pragma("unroll")                                                          \
    for (int fn_ = 0; fn_ < 3; ++fn_) {                                        \
      acc[0][fn_] = __builtin_amdgcn_mfma_f32_16x16x32_bf16(a0_, BUSE[fn_], acc[0][fn_], 0, 0, 0); \
      acc[1][fn_] = __builtin_amdgcn_mfma_f32_16x16x32_bf16(a1_, BUSE[fn_], acc[1][fn_], 0, 0, 0); \
      acc[2][fn_] = __builtin_amdgcn_mfma_f32_16x16x32_bf16(a2_, BUSE[fn_], acc[2][fn_], 0, 0, 0); \
      acc[3][fn_] = __builtin_amdgcn_mfma_f32_16x16x32_bf16(a3_, BUSE[fn_], acc[3][fn_], 0, 0, 0); \
    }                                                                          \
    __builtin_amdgcn_s_setprio(0);                                             \
  }

#define WAITV7 asm volatile("s_waitcnt vmcnt(7)" ::: "memory")
#define WAITV3 asm volatile("s_waitcnt vmcnt(3)" ::: "memory")

#define STEP(T, BSEL, BUSE, BLOAD, DOISSUE, WMACRO)                            \
  {                                                                            \
    WMACRO;                                                                    \
    __builtin_amdgcn_sched_barrier(0);                                         \
    __builtin_amdgcn_s_barrier();                                              \
    __builtin_amdgcn_sched_barrier(0);                                         \
    if (DOISSUE) {                                                             \
      STAGEA((T) + 2, ((BSEL) + 2) % 3);                                       \
      LOADB(BLOAD, (T) + 2);                                                   \
      __builtin_amdgcn_sched_barrier(0);                                       \
    }                                                                          \
    COMPUTE(BSEL, BUSE);                                                       \
  }

  // prologue: tiles 0 and 1 in flight (A then B per tile -> queue A0,B0x3,A1,B1x3)
  STAGEA(0, 0);
  LOADB(b0, 0);
  STAGEA(1, 1);
  LOADB(b1, 1);

  int t = 0;
#pragma unroll 1
  for (int it = 0; it < 9; ++it) {                  // t = 0..26
    STEP(t + 0, 0, b0, b2, true, WAITV7);
    STEP(t + 1, 1, b1, b0, true, WAITV7);
    STEP(t + 2, 2, b2, b1, true, WAITV7);
    t += 3;
  }
  STEP(27, 0, b0, b2, true, WAITV7);                // issues tile 29
  STEP(28, 1, b1, b0, false, WAITV7);
  STEP(29, 2, b2, b1, false, WAITV3);

#undef STEP
#undef WAITV7
#undef WAITV3
#undef COMPUTE
#undef LOADB
#undef STAGEA

  __syncthreads();                                  // bufs -> act reuse

  // epilogue: 4 chunks of 32 rows; bias+relu -> LDS -> per-(row,group) max over 38 channels.
  // Fully unrolled: every acc[] index compile-time (rule #20).
#pragma unroll
  for (int ch = 0; ch < 4; ++ch) {
    if (wr == (ch >> 1)) {
      const int fbase = (ch & 1) * 2;
#pragma unroll
      for (int fi = 0; fi < 2; ++fi) {
#pragma unroll
        for (int fn = 0; fn < 3; ++fn) {
          const int col = wc * 48 + fn * 16 + l15;   // < 192 < 210
          const float bias = convb[col];
#pragma unroll
          for (int rg = 0; rg < 4; ++rg) {
            const int rloc = fi * 16 + l4 * 4 + rg;  // 0..31 within chunk
            float vv = acc[fbase + fi][fn][rg] + bias;
            act[rloc * 194 + col] = fmaxf(vv, 0.f);
          }
        }
      }
    }
    __syncthreads();
    if (tid < 160) {                                  // 32 rows x 5 groups
      const int rl = tid / 5, gq = tid - rl * 5;
      const float* ap = act + rl * 194 + gq * KPOOL;
      float mx = 0.f;                                 // relu => values >= 0
#pragma unroll
      for (int i = 0; i < KPOOL; ++i) mx = fmaxf(mx, ap[i]);
      const int m = m0 + ch * 32 + rl;
      const int bb = m / SEQ, ss = m - bb * SEQ;
      maxc[(bb * NBLK + gq) * SEQ + ss] = mx;         // unmasked max; mask applied in k_dense
    }
    __syncthreads();
  }
}

// ---- kernel 4: region-masked dense (120->35) + out (35->35) ----
__global__ __launch_bounds__(256) void k_dense(const float* __restrict__ maxc,
                                               const int* __restrict__ pos,
                                               const float* __restrict__ dw,
                                               const float* __restrict__ db,
                                               const float* __restrict__ ow,
                                               const float* __restrict__ ob,
                                               float* __restrict__ out) {
  __shared__ float dwL[120 * 36];
  __shared__ float owL[35 * 36];
  __shared__ float hL[64 * 36];
  __shared__ float mxL[64 * 40];
  const int tid = threadIdx.x;
  const int r0 = blockIdx.x * 64;                    // 640 blocks x 64 rows
  for (int i = tid; i < 120 * 35; i += 256) { int j = i / 35, d = i - j * 35; dwL[j * 36 + d] = dw[i]; }
  for (int i = tid; i < 35 * 35; i += 256)  { int j = i / 35, d = i - j * 35; owL[j * 36 + d] = ow[i]; }
  for (int i = tid; i < 64 * 40; i += 256)  mxL[i] = maxc[(size_t)r0 * 40 + i];
  __syncthreads();
  for (int t = tid; t < 64 * 35; t += 256) {
    const int row = t / 35, d = t - row * 35;
    const int rg = r0 + row;
    const int b = rg / NBLK;
    const int p0 = pos[b * 2], p1 = pos[b * 2 + 1];
    int e1 = min(p0, p1), e2 = max(p0, p1);
    if (e1 == 0) { e1 = 1; e2 += 1; }
    float a = db[d];
#pragma unroll
    for (int s = 0; s < SEQ; ++s) {
      const int k = (s >= e1) + (s >= e2);           // region of position s
      a += mxL[row * 40 + s] * dwL[(k * SEQ + s) * 36 + d];
    }
    hL[row * 36 + d] = a;
  }
  __syncthreads();
  for (int t = tid; t < 64 * 35; t += 256) {
    const int row = t / 35, c = t - row * 35;
    float a = ob[c];
#pragma unroll
    for (int d = 0; d < DH; ++d) a += hL[row * 36 + d] * owL[d * 36 + c];
    out[(size_t)(r0 + row) * NCLS + c] = a;
  }
}

extern "C" void kernel_launch(void* const* d_in, const int* in_sizes, int n_in,
                              void* d_out, int out_size, void* d_ws, size_t ws_size,
                              hipStream_t stream) {
  const int*   x     = (const int*)d_in[0];
  const int*   pos   = (const int*)d_in[1];
  const float* w2v   = (const float*)d_in[2];
  const float* convw = (const float*)d_in[3];
  const float* convb = (const float*)d_in[4];
  const float* dw    = (const float*)d_in[5];
  const float* db    = (const float*)d_in[6];
  const float* ow    = (const float*)d_in[7];
  const float* ob    = (const float*)d_in[8];
  float* out = (float*)d_out;

  char* ws = (char*)d_ws;
  u16* W    = (u16*)ws;                               // (100001)*320*2 = 64,000,640 B
  u16* Btn  = (u16*)(ws + 64000640);                  // 120*192*8*2   =    368,640 B
  float* maxc = (float*)(ws + 64000640 + 368640);     // 40960*40*4    =  6,553,600 B

  k_prepW<<<15626, 256, 0, stream>>>(w2v, W);         // (100001*40+255)/256
  k_prepB<<<90, 256, 0, stream>>>(convw, Btn);        // 23040/256
  k_conv_gemm<<<2560, 512, 0, stream>>>(W, Btn, x, convb, maxc);  // 327680/128
  k_dense<<<640, 256, 0, stream>>>(maxc, pos, dw, db, ow, ob, out);
}